// Round 2
// baseline (267.295 us; speedup 1.0000x reference)
//
#include <hip/hip_runtime.h>
#include <hip/hip_bf16.h>

typedef __bf16 bf16;
typedef __bf16 bf16x8 __attribute__((ext_vector_type(8)));
typedef float f32x4 __attribute__((ext_vector_type(4)));
typedef unsigned short u16;

// workspace offsets (bytes)
static constexpr size_t OFF_Q    = 0;          // [16][8][1024][32] bf16
static constexpr size_t OFF_K    = 8388608;    // [16][8][1024][32] bf16
static constexpr size_t OFF_VT   = 16777216;   // [16][8][32][1024] bf16 (V transposed)
static constexpr size_t OFF_Y    = 25165824;   // [16][1024][256]  bf16 (attn out)
static constexpr size_t OFF_COMB = 33554432;   // [2][8][64][64]   f32  (bias tables)

__device__ __forceinline__ int clampi(int v, int lo, int hi) {
  return v < lo ? lo : (v > hi ? hi : v);
}

// load 8 consecutive fp32 and round to bf16x8 (MFMA fragment)
__device__ __forceinline__ bf16x8 ldcvt8(const float* p) {
  f32x4 a = *(const f32x4*)p;
  f32x4 b = *(const f32x4*)(p + 4);
  bf16x8 r;
  r[0] = (bf16)a[0]; r[1] = (bf16)a[1]; r[2] = (bf16)a[2]; r[3] = (bf16)a[3];
  r[4] = (bf16)b[0]; r[5] = (bf16)b[1]; r[6] = (bf16)b[2]; r[7] = (bf16)b[3];
  return r;
}

// ---------------- kernel 1: combined bias table ----------------
// comb[b][h][a][c] = table_t[a-c+63][h] + tx[binx(a%16,c%16)][h] + ty[..][h] + tz[..][h]
__global__ void build_comb_k(const float* __restrict__ loc, const float* __restrict__ tt,
                             const float* __restrict__ tx, const float* __restrict__ ty,
                             const float* __restrict__ tz, float* __restrict__ comb) {
  const int b = blockIdx.x >> 3, h = blockIdx.x & 7;
  __shared__ float st[256];
  const int t = threadIdx.x;
  {
    const int i = t >> 4, j = t & 15;
    const float* li = loc + (b * 16 + i) * 3;
    const float* lj = loc + (b * 16 + j) * 3;
    const float G = (float)(111.32 / 100.0);  // f32 math matches jax/np f32 ref
    float dx = li[0] - lj[0];
    float dy = li[1] - lj[1];
    float dz = li[2] - lj[2];
    int ix = clampi((int)rintf(dx / G + 25.0f), 0, 50);
    int iy = clampi((int)rintf(dy / G + 25.0f), 0, 50);
    int iz = clampi((int)rintf(dz / G + 5.0f), 0, 10);
    st[t] = tx[ix * 8 + h] + ty[iy * 8 + h] + tz[iz * 8 + h];
  }
  __syncthreads();
  float* out = comb + blockIdx.x * 4096;
  for (int e = t; e < 4096; e += 256) {
    int a = e >> 6, c = e & 63;
    out[e] = tt[(a - c + 63) * 8 + h] + st[((a & 15) << 4) | (c & 15)];
  }
}

// ---------------- kernel 2: QKV GEMM (roll fused into A gather) ----------------
__global__ __launch_bounds__(256) void qkv_k(const float* __restrict__ x, const float* __restrict__ w,
                                             const float* __restrict__ qb, bf16* __restrict__ qws,
                                             bf16* __restrict__ kws, bf16* __restrict__ vtws) {
  const int lane = threadIdx.x & 63, wv = threadIdx.x >> 6;
  const int rr = lane & 15, g = lane >> 4;
  const int mb = blockIdx.x * 64;
  const int nb = blockIdx.y * 64 + wv * 16;
  const float* aptr[4];
#pragma unroll
  for (int rt = 0; rt < 4; ++rt) {
    int m = mb + rt * 16 + rr;
    int wid = m >> 10, n = m & 1023;
    int bb = wid >> 3, wi = wid & 7, tw = n >> 4, ww = n & 15;
    int hh = (wi * 64 + tw + 32) & 511;            // roll(x, -32)
    aptr[rt] = x + (((bb * 512 + hh) * 16 + ww) << 8);
  }
  const float* bptr = w + (nb + rr) * 256;
  f32x4 acc[4] = {};
#pragma unroll
  for (int k8 = 0; k8 < 8; ++k8) {
    const int ko = k8 * 32 + g * 8;
    bf16x8 bfrag = ldcvt8(bptr + ko);
#pragma unroll
    for (int rt = 0; rt < 4; ++rt) {
      bf16x8 afrag = ldcvt8(aptr[rt] + ko);
      acc[rt] = __builtin_amdgcn_mfma_f32_16x16x32_bf16(afrag, bfrag, acc[rt], 0, 0, 0);
    }
  }
  const int c = nb + rr;
  const float bc = qb[c];
  const int qkvi = c >> 8, hh = (c & 255) >> 5, d = c & 31;
#pragma unroll
  for (int rt = 0; rt < 4; ++rt) {
    const int n0 = mb + rt * 16 + g * 4;
    const int wid = n0 >> 10, nw0 = n0 & 1023;
    if (qkvi == 2) {
      union { u16 us[4]; uint2 u2; } pk;
#pragma unroll
      for (int r = 0; r < 4; ++r) {
        bf16 bv = (bf16)(acc[rt][r] + bc);
        pk.us[r] = *(const u16*)&bv;
      }
      *(uint2*)(vtws + (((wid * 8 + hh) * 32 + d) << 10) + nw0) = pk.u2;
    } else {
      bf16* base = (qkvi ? kws : qws) + ((wid * 8 + hh) << 15) + (nw0 << 5) + d;
#pragma unroll
      for (int r = 0; r < 4; ++r) base[r << 5] = (bf16)(acc[rt][r] + bc);
    }
  }
}

// ---------------- kernel 3: flash attention, swapped-operand S^T ----------------
__global__ __launch_bounds__(256) void attn_k(const bf16* __restrict__ qws, const bf16* __restrict__ kws,
                                              const bf16* __restrict__ vtws, const float* __restrict__ comb,
                                              bf16* __restrict__ yws) {
  const int lane = threadIdx.x & 63, wv = threadIdx.x >> 6;
  const int rr = lane & 15, g = lane >> 4;
  const int qt = blockIdx.x, h = blockIdx.y, wid = blockIdx.z;
  const int b = wid >> 3;
  const bool win7 = (wid & 7) == 7;
  const int i = qt * 64 + wv * 16 + rr;            // query row (thread-local!)
  const bf16* qbase = qws + ((size_t)(wid * 8 + h) << 15);
  const bf16* kbase = kws + ((size_t)(wid * 8 + h) << 15);
  const bf16* vbase = vtws + ((size_t)(wid * 8 + h) << 15);
  const bf16x8 qfrag = *(const bf16x8*)(qbase + (i << 5) + g * 8);
  const float* crow = comb + (b * 8 + h) * 4096 + (i & 63) * 64;
  f32x4 breg[2][2];
  breg[0][0] = *(const f32x4*)(crow + g * 8);
  breg[0][1] = *(const f32x4*)(crow + g * 8 + 4);
  breg[1][0] = *(const f32x4*)(crow + 32 + g * 8);
  breg[1][1] = *(const f32x4*)(crow + 32 + g * 8 + 4);
  const bool ilow = i < 512;
  const int kp = 8 * (rr >> 2) + (rr & 3);         // permuted K-row so P^T feeds PV B-frag
  const float scale = 0.17677669529663687f;        // 32^-0.5
  float m_run = -1e30f, l_run = 0.0f;
  f32x4 o0 = {}, o1 = {};                          // O^T rows d=4g+r (+16), col i
  for (int kb = 0; kb < 1024; kb += 32) {
    bf16x8 ka0 = *(const bf16x8*)(kbase + ((kb + kp) << 5) + g * 8);
    bf16x8 ka1 = *(const bf16x8*)(kbase + ((kb + kp + 4) << 5) + g * 8);
    f32x4 zero = {};
    f32x4 s0 = __builtin_amdgcn_mfma_f32_16x16x32_bf16(ka0, qfrag, zero, 0, 0, 0);
    f32x4 s1 = __builtin_amdgcn_mfma_f32_16x16x32_bf16(ka1, qfrag, zero, 0, 0, 0);
    const int ph = (kb >> 5) & 1;
    const float madd = (win7 && (ilow != (kb < 512))) ? -100.0f : 0.0f;
    f32x4 v0, v1;
#pragma unroll
    for (int r = 0; r < 4; ++r) {
      v0[r] = s0[r] * scale + breg[ph][0][r] + madd;   // key j = kb + 8g + r
      v1[r] = s1[r] * scale + breg[ph][1][r] + madd;   // key j = kb + 8g + 4 + r
    }
    float m8 = fmaxf(fmaxf(fmaxf(v0[0], v0[1]), fmaxf(v0[2], v0[3])),
                     fmaxf(fmaxf(v1[0], v1[1]), fmaxf(v1[2], v1[3])));
    m8 = fmaxf(m8, __shfl_xor(m8, 16));
    m8 = fmaxf(m8, __shfl_xor(m8, 32));
    const float m_new = fmaxf(m_run, m8);
    const float corr = __expf(m_run - m_new);
    float p0[4], p1[4];
    float s8 = 0.0f;
#pragma unroll
    for (int r = 0; r < 4; ++r) { p0[r] = __expf(v0[r] - m_new); s8 += p0[r]; }
#pragma unroll
    for (int r = 0; r < 4; ++r) { p1[r] = __expf(v1[r] - m_new); s8 += p1[r]; }
    s8 += __shfl_xor(s8, 16);
    s8 += __shfl_xor(s8, 32);
    l_run = l_run * corr + s8;
    m_run = m_new;
    bf16x8 pa;
#pragma unroll
    for (int r = 0; r < 4; ++r) { pa[r] = (bf16)p0[r]; pa[r + 4] = (bf16)p1[r]; }
#pragma unroll
    for (int r = 0; r < 4; ++r) { o0[r] *= corr; o1[r] *= corr; }
    bf16x8 va0 = *(const bf16x8*)(vbase + (rr << 10) + kb + g * 8);
    bf16x8 va1 = *(const bf16x8*)(vbase + ((16 + rr) << 10) + kb + g * 8);
    o0 = __builtin_amdgcn_mfma_f32_16x16x32_bf16(va0, pa, o0, 0, 0, 0);
    o1 = __builtin_amdgcn_mfma_f32_16x16x32_bf16(va1, pa, o1, 0, 0, 0);
  }
  const float inv = 1.0f / l_run;
  bf16* ybase = yws + (size_t)((wid << 10) + i) * 256 + h * 32;
  union { u16 us[4]; uint2 u2; } pk;
#pragma unroll
  for (int r = 0; r < 4; ++r) { bf16 bv = (bf16)(o0[r] * inv); pk.us[r] = *(const u16*)&bv; }
  *(uint2*)(ybase + g * 4) = pk.u2;
#pragma unroll
  for (int r = 0; r < 4; ++r) { bf16 bv = (bf16)(o1[r] * inv); pk.us[r] = *(const u16*)&bv; }
  *(uint2*)(ybase + 16 + g * 4) = pk.u2;
}

// ---------------- kernel 4: proj GEMM (+roll back, fused into C scatter) ----------------
__global__ __launch_bounds__(256) void proj_k(const bf16* __restrict__ yws, const float* __restrict__ w,
                                              const float* __restrict__ pb, float* __restrict__ out) {
  const int lane = threadIdx.x & 63, wv = threadIdx.x >> 6;
  const int rr = lane & 15, g = lane >> 4;
  const int mb = blockIdx.x * 64;
  const int nb = blockIdx.y * 64 + wv * 16;
  const float* bptr = w + (nb + rr) * 256;
  f32x4 acc[4] = {};
#pragma unroll
  for (int k8 = 0; k8 < 8; ++k8) {
    const int ko = k8 * 32 + g * 8;
    bf16x8 bfrag = ldcvt8(bptr + ko);
#pragma unroll
    for (int rt = 0; rt < 4; ++rt) {
      bf16x8 afrag = *(const bf16x8*)(yws + (mb + rt * 16 + rr) * 256 + ko);
      acc[rt] = __builtin_amdgcn_mfma_f32_16x16x32_bf16(afrag, bfrag, acc[rt], 0, 0, 0);
    }
  }
  const int c = nb + rr;
  const float bc = pb[c];
#pragma unroll
  for (int rt = 0; rt < 4; ++rt) {
#pragma unroll
    for (int r = 0; r < 4; ++r) {
      const int m = mb + rt * 16 + g * 4 + r;
      const int wid = m >> 10, n = m & 1023;
      const int bb = wid >> 3;
      const int hh = ((wid & 7) * 64 + (n >> 4) + 32) & 511;  // roll(out, +32)
      out[(((bb * 512 + hh) * 16 + (n & 15)) << 8) + c] = acc[rt][r] + bc;
    }
  }
}

extern "C" void kernel_launch(void* const* d_in, const int* in_sizes, int n_in,
                              void* d_out, int out_size, void* d_ws, size_t ws_size,
                              hipStream_t stream) {
  const float* x     = (const float*)d_in[0];
  const float* loc   = (const float*)d_in[1];
  const float* qkvw  = (const float*)d_in[2];
  const float* qkvb  = (const float*)d_in[3];
  const float* projw = (const float*)d_in[4];
  const float* projb = (const float*)d_in[5];
  const float* tt    = (const float*)d_in[6];
  const float* tx    = (const float*)d_in[7];
  const float* ty    = (const float*)d_in[8];
  const float* tz    = (const float*)d_in[9];
  char* ws = (char*)d_ws;
  bf16* qws   = (bf16*)(ws + OFF_Q);
  bf16* kws   = (bf16*)(ws + OFF_K);
  bf16* vtws  = (bf16*)(ws + OFF_VT);
  bf16* yws   = (bf16*)(ws + OFF_Y);
  float* comb = (float*)(ws + OFF_COMB);
  float* out = (float*)d_out;

  build_comb_k<<<16, 256, 0, stream>>>(loc, tt, tx, ty, tz, comb);
  qkv_k<<<dim3(256, 12), 256, 0, stream>>>(x, qkvw, qkvb, qws, kws, vtws);
  attn_k<<<dim3(16, 8, 16), 256, 0, stream>>>(qws, kws, vtws, comb, yws);
  proj_k<<<dim3(256, 4), 256, 0, stream>>>(yws, projw, projb, out);
}

// Round 3
// 249.295 us; speedup vs baseline: 1.0722x; 1.0722x over previous
//
#include <hip/hip_runtime.h>
#include <hip/hip_bf16.h>

typedef __bf16 bf16;
typedef __bf16 bf16x8 __attribute__((ext_vector_type(8)));
typedef float f32x4 __attribute__((ext_vector_type(4)));
typedef unsigned short u16;

// workspace offsets (bytes)
static constexpr size_t OFF_Q    = 0;          // [16][8][1024][32] bf16
static constexpr size_t OFF_K    = 8388608;    // [16][8][1024][32] bf16
static constexpr size_t OFF_VT   = 16777216;   // [16][8][32][1024] bf16 (V transposed)
static constexpr size_t OFF_Y    = 25165824;   // [16][1024][256]  bf16 (attn out)
static constexpr size_t OFF_COMB = 33554432;   // [2][8][64][64]   f32  (bias tables)

__device__ __forceinline__ int clampi(int v, int lo, int hi) {
  return v < lo ? lo : (v > hi ? hi : v);
}

// load 8 consecutive fp32 and round to bf16x8 (MFMA fragment)
__device__ __forceinline__ bf16x8 ldcvt8(const float* p) {
  f32x4 a = *(const f32x4*)p;
  f32x4 b = *(const f32x4*)(p + 4);
  bf16x8 r;
  r[0] = (bf16)a[0]; r[1] = (bf16)a[1]; r[2] = (bf16)a[2]; r[3] = (bf16)a[3];
  r[4] = (bf16)b[0]; r[5] = (bf16)b[1]; r[6] = (bf16)b[2]; r[7] = (bf16)b[3];
  return r;
}

// ---------------- kernel 1: combined bias table ----------------
__global__ void build_comb_k(const float* __restrict__ loc, const float* __restrict__ tt,
                             const float* __restrict__ tx, const float* __restrict__ ty,
                             const float* __restrict__ tz, float* __restrict__ comb) {
  const int b = blockIdx.x >> 3, h = blockIdx.x & 7;
  __shared__ float st[256];
  const int t = threadIdx.x;
  {
    const int i = t >> 4, j = t & 15;
    const float* li = loc + (b * 16 + i) * 3;
    const float* lj = loc + (b * 16 + j) * 3;
    const float G = (float)(111.32 / 100.0);
    float dx = li[0] - lj[0];
    float dy = li[1] - lj[1];
    float dz = li[2] - lj[2];
    int ix = clampi((int)rintf(dx / G + 25.0f), 0, 50);
    int iy = clampi((int)rintf(dy / G + 25.0f), 0, 50);
    int iz = clampi((int)rintf(dz / G + 5.0f), 0, 10);
    st[t] = tx[ix * 8 + h] + ty[iy * 8 + h] + tz[iz * 8 + h];
  }
  __syncthreads();
  float* out = comb + blockIdx.x * 4096;
  for (int e = t; e < 4096; e += 256) {
    int a = e >> 6, c = e & 63;
    out[e] = tt[(a - c + 63) * 8 + h] + st[((a & 15) << 4) | (c & 15)];
  }
}

// ---------------- kernel 2: QKV GEMM (roll fused into A gather) ----------------
__global__ __launch_bounds__(256) void qkv_k(const float* __restrict__ x, const float* __restrict__ w,
                                             const float* __restrict__ qb, bf16* __restrict__ qws,
                                             bf16* __restrict__ kws, bf16* __restrict__ vtws) {
  const int lane = threadIdx.x & 63, wv = threadIdx.x >> 6;
  const int rr = lane & 15, g = lane >> 4;
  const int mb = blockIdx.x * 64;
  const int nb = blockIdx.y * 64 + wv * 16;
  const float* aptr[4];
#pragma unroll
  for (int rt = 0; rt < 4; ++rt) {
    int m = mb + rt * 16 + rr;
    int wid = m >> 10, n = m & 1023;
    int bb = wid >> 3, wi = wid & 7, tw = n >> 4, ww = n & 15;
    int hh = (wi * 64 + tw + 32) & 511;            // roll(x, -32)
    aptr[rt] = x + (((bb * 512 + hh) * 16 + ww) << 8);
  }
  const float* bptr = w + (nb + rr) * 256;
  f32x4 acc[4] = {};
#pragma unroll
  for (int k8 = 0; k8 < 8; ++k8) {
    const int ko = k8 * 32 + g * 8;
    bf16x8 bfrag = ldcvt8(bptr + ko);
#pragma unroll
    for (int rt = 0; rt < 4; ++rt) {
      bf16x8 afrag = ldcvt8(aptr[rt] + ko);
      acc[rt] = __builtin_amdgcn_mfma_f32_16x16x32_bf16(afrag, bfrag, acc[rt], 0, 0, 0);
    }
  }
  const int c = nb + rr;
  const float bc = qb[c];
  const int qkvi = c >> 8, hh = (c & 255) >> 5, d = c & 31;
#pragma unroll
  for (int rt = 0; rt < 4; ++rt) {
    const int n0 = mb + rt * 16 + g * 4;
    const int wid = n0 >> 10, nw0 = n0 & 1023;
    if (qkvi == 2) {
      union { u16 us[4]; uint2 u2; } pk;
#pragma unroll
      for (int r = 0; r < 4; ++r) {
        bf16 bv = (bf16)(acc[rt][r] + bc);
        pk.us[r] = *(const u16*)&bv;
      }
      *(uint2*)(vtws + (((wid * 8 + hh) * 32 + d) << 10) + nw0) = pk.u2;
    } else {
      bf16* base = (qkvi ? kws : qws) + ((wid * 8 + hh) << 15) + (nw0 << 5) + d;
#pragma unroll
      for (int r = 0; r < 4; ++r) base[r << 5] = (bf16)(acc[rt][r] + bc);
    }
  }
}

// ---------------- kernel 3: flash attention v2 ----------------
// 64-key chunks, register-double-buffered K prefetch, XCD-aware block swizzle.
__global__ __launch_bounds__(256, 4) void attn_k(const bf16* __restrict__ qws, const bf16* __restrict__ kws,
                                                 const bf16* __restrict__ vtws, const float* __restrict__ comb,
                                                 bf16* __restrict__ yws) {
  const int lane = threadIdx.x & 63, wv = threadIdx.x >> 6;
  const int rr = lane & 15, g = lane >> 4;
  // XCD swizzle: id%8 = XCD (round-robin dispatch); all 16 qt-blocks of one
  // (h,wid) group land on the same XCD -> K/V stay L2-resident (3 MB/XCD).
  const int id = blockIdx.x;
  const int xcd = id & 7, t2 = id >> 3;
  const int qt = t2 & 15, gh = t2 >> 4;
  const int grp = gh * 8 + xcd;                    // bijective, 2048 % 8 == 0
  const int h = grp & 7, wid = grp >> 3;
  const int b = wid >> 3;
  const bool win7 = (wid & 7) == 7;
  const int i = qt * 64 + wv * 16 + rr;            // query row (thread-local)
  const bf16* qbase = qws + ((size_t)(wid * 8 + h) << 15);
  const bf16* kbase = kws + ((size_t)(wid * 8 + h) << 15);
  const bf16* vbase = vtws + ((size_t)(wid * 8 + h) << 15);
  const bf16x8 qfrag = *(const bf16x8*)(qbase + (i << 5) + g * 8);
  const float* crow = comb + (b * 8 + h) * 4096 + (i & 63) * 64;
  f32x4 breg[2][2];
  breg[0][0] = *(const f32x4*)(crow + g * 8);        // keys kb + 8g + r
  breg[0][1] = *(const f32x4*)(crow + g * 8 + 4);    // keys kb + 8g + 4 + r
  breg[1][0] = *(const f32x4*)(crow + 32 + g * 8);   // keys kb+32 + 8g + r
  breg[1][1] = *(const f32x4*)(crow + 32 + g * 8 + 4);
  const bool ilow = i < 512;
  const int kp = 8 * (rr >> 2) + (rr & 3);         // permuted K-row so P^T feeds PV B-frag
  const float scale = 0.17677669529663687f;        // 32^-0.5
  float m_run = -1e30f, l_run = 0.0f;
  f32x4 o0 = {}, o1 = {};                          // O^T rows d=4g+r (+16), col i

  const bf16* krow = kbase + (kp << 5) + g * 8;    // row stride 32 elems
  const bf16* vrow0 = vbase + (rr << 10) + g * 8;
  const bf16* vrow1 = vbase + ((16 + rr) << 10) + g * 8;

  // prologue: chunk 0 K fragments
  bf16x8 cK0 = *(const bf16x8*)(krow);
  bf16x8 cK1 = *(const bf16x8*)(krow + (4 << 5));
  bf16x8 cK2 = *(const bf16x8*)(krow + (32 << 5));
  bf16x8 cK3 = *(const bf16x8*)(krow + (36 << 5));

#pragma unroll
  for (int t = 0; t < 16; ++t) {
    const int kb = t * 64;
    // current chunk V loads (consumed after softmax -> latency hidden)
    bf16x8 v00 = *(const bf16x8*)(vrow0 + kb);
    bf16x8 v01 = *(const bf16x8*)(vrow0 + kb + 32);
    bf16x8 v10 = *(const bf16x8*)(vrow1 + kb);
    bf16x8 v11 = *(const bf16x8*)(vrow1 + kb + 32);
    // next chunk K prefetch (consumed next iteration)
    bf16x8 nK0, nK1, nK2, nK3;
    if (t < 15) {
      const bf16* kn = krow + ((kb + 64) << 5);
      nK0 = *(const bf16x8*)(kn);
      nK1 = *(const bf16x8*)(kn + (4 << 5));
      nK2 = *(const bf16x8*)(kn + (32 << 5));
      nK3 = *(const bf16x8*)(kn + (36 << 5));
    } else {
      nK0 = cK0; nK1 = cK1; nK2 = cK2; nK3 = cK3;
    }
    f32x4 zero = {};
    f32x4 s0 = __builtin_amdgcn_mfma_f32_16x16x32_bf16(cK0, qfrag, zero, 0, 0, 0);
    f32x4 s1 = __builtin_amdgcn_mfma_f32_16x16x32_bf16(cK1, qfrag, zero, 0, 0, 0);
    f32x4 s2 = __builtin_amdgcn_mfma_f32_16x16x32_bf16(cK2, qfrag, zero, 0, 0, 0);
    f32x4 s3 = __builtin_amdgcn_mfma_f32_16x16x32_bf16(cK3, qfrag, zero, 0, 0, 0);
    const float madd = (win7 && (ilow != (kb < 512))) ? -100.0f : 0.0f;
    f32x4 v0, v1, v2, v3;
#pragma unroll
    for (int r = 0; r < 4; ++r) {
      v0[r] = s0[r] * scale + breg[0][0][r] + madd;   // key kb + 8g + r
      v1[r] = s1[r] * scale + breg[0][1][r] + madd;   // key kb + 8g + 4 + r
      v2[r] = s2[r] * scale + breg[1][0][r] + madd;   // key kb+32 + 8g + r
      v3[r] = s3[r] * scale + breg[1][1][r] + madd;   // key kb+32 + 8g + 4 + r
    }
    float m16 = fmaxf(fmaxf(fmaxf(fmaxf(v0[0], v0[1]), fmaxf(v0[2], v0[3])),
                            fmaxf(fmaxf(v1[0], v1[1]), fmaxf(v1[2], v1[3]))),
                      fmaxf(fmaxf(fmaxf(v2[0], v2[1]), fmaxf(v2[2], v2[3])),
                            fmaxf(fmaxf(v3[0], v3[1]), fmaxf(v3[2], v3[3]))));
    m16 = fmaxf(m16, __shfl_xor(m16, 16));
    m16 = fmaxf(m16, __shfl_xor(m16, 32));
    const float m_new = fmaxf(m_run, m16);
    const float corr = __expf(m_run - m_new);
    float p0[4], p1[4], p2[4], p3[4];
    float s16 = 0.0f;
#pragma unroll
    for (int r = 0; r < 4; ++r) {
      p0[r] = __expf(v0[r] - m_new); p1[r] = __expf(v1[r] - m_new);
      p2[r] = __expf(v2[r] - m_new); p3[r] = __expf(v3[r] - m_new);
      s16 += p0[r] + p1[r] + p2[r] + p3[r];
    }
    s16 += __shfl_xor(s16, 16);
    s16 += __shfl_xor(s16, 32);
    l_run = l_run * corr + s16;
    m_run = m_new;
    bf16x8 paL, paH;
#pragma unroll
    for (int r = 0; r < 4; ++r) {
      paL[r] = (bf16)p0[r]; paL[r + 4] = (bf16)p1[r];
      paH[r] = (bf16)p2[r]; paH[r + 4] = (bf16)p3[r];
    }
#pragma unroll
    for (int r = 0; r < 4; ++r) { o0[r] *= corr; o1[r] *= corr; }
    o0 = __builtin_amdgcn_mfma_f32_16x16x32_bf16(v00, paL, o0, 0, 0, 0);
    o0 = __builtin_amdgcn_mfma_f32_16x16x32_bf16(v01, paH, o0, 0, 0, 0);
    o1 = __builtin_amdgcn_mfma_f32_16x16x32_bf16(v10, paL, o1, 0, 0, 0);
    o1 = __builtin_amdgcn_mfma_f32_16x16x32_bf16(v11, paH, o1, 0, 0, 0);
    cK0 = nK0; cK1 = nK1; cK2 = nK2; cK3 = nK3;
  }
  const float inv = 1.0f / l_run;
  bf16* ybase = yws + (size_t)((wid << 10) + i) * 256 + h * 32;
  union { u16 us[4]; uint2 u2; } pk;
#pragma unroll
  for (int r = 0; r < 4; ++r) { bf16 bv = (bf16)(o0[r] * inv); pk.us[r] = *(const u16*)&bv; }
  *(uint2*)(ybase + g * 4) = pk.u2;
#pragma unroll
  for (int r = 0; r < 4; ++r) { bf16 bv = (bf16)(o1[r] * inv); pk.us[r] = *(const u16*)&bv; }
  *(uint2*)(ybase + 16 + g * 4) = pk.u2;
}

// ---------------- kernel 4: proj GEMM (+roll back, fused into C scatter) ----------------
__global__ __launch_bounds__(256) void proj_k(const bf16* __restrict__ yws, const float* __restrict__ w,
                                              const float* __restrict__ pb, float* __restrict__ out) {
  const int lane = threadIdx.x & 63, wv = threadIdx.x >> 6;
  const int rr = lane & 15, g = lane >> 4;
  const int mb = blockIdx.x * 64;
  const int nb = blockIdx.y * 64 + wv * 16;
  const float* bptr = w + (nb + rr) * 256;
  f32x4 acc[4] = {};
#pragma unroll
  for (int k8 = 0; k8 < 8; ++k8) {
    const int ko = k8 * 32 + g * 8;
    bf16x8 bfrag = ldcvt8(bptr + ko);
#pragma unroll
    for (int rt = 0; rt < 4; ++rt) {
      bf16x8 afrag = *(const bf16x8*)(yws + (mb + rt * 16 + rr) * 256 + ko);
      acc[rt] = __builtin_amdgcn_mfma_f32_16x16x32_bf16(afrag, bfrag, acc[rt], 0, 0, 0);
    }
  }
  const int c = nb + rr;
  const float bc = pb[c];
#pragma unroll
  for (int rt = 0; rt < 4; ++rt) {
#pragma unroll
    for (int r = 0; r < 4; ++r) {
      const int m = mb + rt * 16 + g * 4 + r;
      const int wid = m >> 10, n = m & 1023;
      const int bb = wid >> 3;
      const int hh = ((wid & 7) * 64 + (n >> 4) + 32) & 511;  // roll(out, +32)
      out[(((bb * 512 + hh) * 16 + (n & 15)) << 8) + c] = acc[rt][r] + bc;
    }
  }
}

extern "C" void kernel_launch(void* const* d_in, const int* in_sizes, int n_in,
                              void* d_out, int out_size, void* d_ws, size_t ws_size,
                              hipStream_t stream) {
  const float* x     = (const float*)d_in[0];
  const float* loc   = (const float*)d_in[1];
  const float* qkvw  = (const float*)d_in[2];
  const float* qkvb  = (const float*)d_in[3];
  const float* projw = (const float*)d_in[4];
  const float* projb = (const float*)d_in[5];
  const float* tt    = (const float*)d_in[6];
  const float* tx    = (const float*)d_in[7];
  const float* ty    = (const float*)d_in[8];
  const float* tz    = (const float*)d_in[9];
  char* ws = (char*)d_ws;
  bf16* qws   = (bf16*)(ws + OFF_Q);
  bf16* kws   = (bf16*)(ws + OFF_K);
  bf16* vtws  = (bf16*)(ws + OFF_VT);
  bf16* yws   = (bf16*)(ws + OFF_Y);
  float* comb = (float*)(ws + OFF_COMB);
  float* out = (float*)d_out;

  build_comb_k<<<16, 256, 0, stream>>>(loc, tt, tx, ty, tz, comb);
  qkv_k<<<dim3(256, 12), 256, 0, stream>>>(x, qkvw, qkvb, qws, kws, vtws);
  attn_k<<<2048, 256, 0, stream>>>(qws, kws, vtws, comb, yws);
  proj_k<<<dim3(256, 4), 256, 0, stream>>>(yws, projw, projb, out);
}

// Round 4
// 138.132 us; speedup vs baseline: 1.9351x; 1.8048x over previous
//
#include <hip/hip_runtime.h>
#include <hip/hip_bf16.h>

typedef __bf16 bf16;
typedef __bf16 bf16x8 __attribute__((ext_vector_type(8)));
typedef float f32x4 __attribute__((ext_vector_type(4)));
typedef unsigned short u16;

// workspace offsets (bytes)
static constexpr size_t OFF_Q    = 0;          // [16][8][1024][32] bf16
static constexpr size_t OFF_K    = 8388608;    // [16][8][1024][32] bf16
static constexpr size_t OFF_VT   = 16777216;   // [16][8][32][1024] bf16 (V transposed)
static constexpr size_t OFF_Y    = 25165824;   // [16][1024][256]  bf16 (attn out) -- xb aliases this (dead until attn)
static constexpr size_t OFF_COMB = 33554432;   // [2][8][64][64]   f32
static constexpr size_t OFF_PWB  = 33816576;   // [256][256]  bf16 proj weight
static constexpr size_t OFF_WB   = 33947648;   // [768][256]  bf16 qkv weight

__device__ __forceinline__ int clampi(int v, int lo, int hi) {
  return v < lo ? lo : (v > hi ? hi : v);
}

__device__ __forceinline__ void glds16(const bf16* src, bf16* dst) {
  __builtin_amdgcn_global_load_lds((const __attribute__((address_space(1))) void*)src,
                                   (__attribute__((address_space(3))) void*)dst,
                                   16, 0, 0);
}

__device__ __forceinline__ bf16x8 cvt8(const float* p) {
  f32x4 a = *(const f32x4*)p;
  f32x4 b = *(const f32x4*)(p + 4);
  bf16x8 r;
  r[0] = (bf16)a[0]; r[1] = (bf16)a[1]; r[2] = (bf16)a[2]; r[3] = (bf16)a[3];
  r[4] = (bf16)b[0]; r[5] = (bf16)b[1]; r[6] = (bf16)b[2]; r[7] = (bf16)b[3];
  return r;
}

// ---------------- kernel 1: combined bias table ----------------
__global__ void build_comb_k(const float* __restrict__ loc, const float* __restrict__ tt,
                             const float* __restrict__ tx, const float* __restrict__ ty,
                             const float* __restrict__ tz, float* __restrict__ comb) {
  const int b = blockIdx.x >> 3, h = blockIdx.x & 7;
  __shared__ float st[256];
  const int t = threadIdx.x;
  {
    const int i = t >> 4, j = t & 15;
    const float* li = loc + (b * 16 + i) * 3;
    const float* lj = loc + (b * 16 + j) * 3;
    const float G = (float)(111.32 / 100.0);
    float dx = li[0] - lj[0];
    float dy = li[1] - lj[1];
    float dz = li[2] - lj[2];
    int ix = clampi((int)rintf(dx / G + 25.0f), 0, 50);
    int iy = clampi((int)rintf(dy / G + 25.0f), 0, 50);
    int iz = clampi((int)rintf(dz / G + 5.0f), 0, 10);
    st[t] = tx[ix * 8 + h] + ty[iy * 8 + h] + tz[iz * 8 + h];
  }
  __syncthreads();
  float* out = comb + blockIdx.x * 4096;
  for (int e = t; e < 4096; e += 256) {
    int a = e >> 6, c = e & 63;
    out[e] = tt[(a - c + 63) * 8 + h] + st[((a & 15) << 4) | (c & 15)];
  }
}

// ---------------- kernel 1b: x fp32 -> xb bf16 [16384][256], roll+window gather fused ----
__global__ __launch_bounds__(256) void cvt_x_k(const float* __restrict__ x, bf16* __restrict__ xb) {
  const int tid = blockIdx.x * 256 + threadIdx.x;
  const int e = tid * 8;
  const int m = e >> 8, k = e & 255;
  const int wid = m >> 10, n = m & 1023;
  const int bb = wid >> 3, wi = wid & 7, tw = n >> 4, ww = n & 15;
  const int hh = (wi * 64 + tw + 32) & 511;          // roll(x, -32)
  const float* src = x + (((bb * 512 + hh) * 16 + ww) << 8) + k;
  *(bf16x8*)(xb + e) = cvt8(src);
}

// ---------------- kernel 1c: qkv weight + proj weight fp32 -> bf16 ----------------
__global__ __launch_bounds__(256) void cvt_w_k(const float* __restrict__ w, const float* __restrict__ pw,
                                               bf16* __restrict__ wb, bf16* __restrict__ pwb) {
  const int tid = blockIdx.x * 256 + threadIdx.x;
  const int e = tid * 8;
  if (e < 768 * 256) {
    *(bf16x8*)(wb + e) = cvt8(w + e);
  } else {
    const int e2 = e - 768 * 256;
    *(bf16x8*)(pwb + e2) = cvt8(pw + e2);
  }
}

// ---------------- kernel 2: QKV GEMM, m97-style LDS-staged, swizzled ----------------
// C[m][c] = sum_k xb[m][k] * wb[c][k]; epilogue scatters to q/k/vT with bias.
__global__ __launch_bounds__(256) void qkv_k(const bf16* __restrict__ xb, const bf16* __restrict__ wb,
                                             const float* __restrict__ qb, bf16* __restrict__ qws,
                                             bf16* __restrict__ kws, bf16* __restrict__ vtws) {
  __shared__ __align__(16) bf16 lA[128 * 64];
  __shared__ __align__(16) bf16 lB[128 * 64];
  const int lane = threadIdx.x & 63, wv = threadIdx.x >> 6;
  const int rr = lane & 15, g = lane >> 4;
  const int wr = wv >> 1, wc = wv & 1;
  // XCD-chunked remap: 768 blocks, 96 per XCD; N-tiles sharing an A-tile adjacent.
  const int bid = blockIdx.x;
  const int tt = (bid & 7) * 96 + (bid >> 3);
  const int mtile = tt / 6, ntile = tt % 6;
  const int mb = mtile * 128, nb2 = ntile * 128;
  // staging lane geometry
  const int arow = lane >> 3;          // row within 8-row insn block (= row&7)
  const int sg = ((lane & 7) ^ arow) << 3;  // swizzled source col offset (elems)
  const int axor = rr & 7;             // read-side XOR
  f32x4 acc[4][4] = {};
  for (int kb = 0; kb < 256; kb += 64) {
#pragma unroll
    for (int q = 0; q < 4; ++q) {
      const int rowp = (wv * 4 + q) * 8 + arow;
      glds16(xb + (mb + rowp) * 256 + kb + sg, &lA[(wv * 4 + q) * 512]);
      glds16(wb + (nb2 + rowp) * 256 + kb + sg, &lB[(wv * 4 + q) * 512]);
    }
    __syncthreads();
#pragma unroll
    for (int ks = 0; ks < 2; ++ks) {
      bf16x8 af[4], bfr[4];
#pragma unroll
      for (int rt = 0; rt < 4; ++rt)
        af[rt] = *(const bf16x8*)&lA[(wr * 64 + rt * 16 + rr) * 64 + (((ks << 2) | g) ^ axor) * 8];
#pragma unroll
      for (int ct = 0; ct < 4; ++ct)
        bfr[ct] = *(const bf16x8*)&lB[(wc * 64 + ct * 16 + rr) * 64 + (((ks << 2) | g) ^ axor) * 8];
#pragma unroll
      for (int rt = 0; rt < 4; ++rt)
#pragma unroll
        for (int ct = 0; ct < 4; ++ct)
          acc[rt][ct] = __builtin_amdgcn_mfma_f32_16x16x32_bf16(af[rt], bfr[ct], acc[rt][ct], 0, 0, 0);
    }
    __syncthreads();
  }
  // epilogue: c2 = global qkv column; block is entirely q, k, or v.
  const int qkvi = (nb2 >> 8);
#pragma unroll
  for (int ct = 0; ct < 4; ++ct) {
    const int c2 = nb2 + wc * 64 + ct * 16 + rr;
    const float bc = qb[c2];
    const int h2 = (c2 & 255) >> 5, d = c2 & 31;
#pragma unroll
    for (int rt = 0; rt < 4; ++rt) {
      const int m0 = mb + wr * 64 + rt * 16 + g * 4;
      const int wid = m0 >> 10, n0 = m0 & 1023;
      if (qkvi == 2) {
        union { u16 us[4]; uint2 u2; } pk;
#pragma unroll
        for (int r = 0; r < 4; ++r) {
          bf16 bv = (bf16)(acc[rt][ct][r] + bc);
          pk.us[r] = *(const u16*)&bv;
        }
        *(uint2*)(vtws + ((size_t)((wid * 8 + h2) * 32 + d) << 10) + n0) = pk.u2;
      } else {
        bf16* bp = (qkvi ? kws : qws) + ((size_t)(wid * 8 + h2) << 15) + d;
#pragma unroll
        for (int r = 0; r < 4; ++r) bp[(size_t)(n0 + r) << 5] = (bf16)(acc[rt][ct][r] + bc);
      }
    }
  }
}

// ---------------- kernel 3: flash attention (unchanged from round 3) ----------------
__global__ __launch_bounds__(256, 4) void attn_k(const bf16* __restrict__ qws, const bf16* __restrict__ kws,
                                                 const bf16* __restrict__ vtws, const float* __restrict__ comb,
                                                 bf16* __restrict__ yws) {
  const int lane = threadIdx.x & 63, wv = threadIdx.x >> 6;
  const int rr = lane & 15, g = lane >> 4;
  const int id = blockIdx.x;
  const int xcd = id & 7, t2 = id >> 3;
  const int qt = t2 & 15, gh = t2 >> 4;
  const int grp = gh * 8 + xcd;
  const int h = grp & 7, wid = grp >> 3;
  const int b = wid >> 3;
  const bool win7 = (wid & 7) == 7;
  const int i = qt * 64 + wv * 16 + rr;
  const bf16* qbase = qws + ((size_t)(wid * 8 + h) << 15);
  const bf16* kbase = kws + ((size_t)(wid * 8 + h) << 15);
  const bf16* vbase = vtws + ((size_t)(wid * 8 + h) << 15);
  const bf16x8 qfrag = *(const bf16x8*)(qbase + (i << 5) + g * 8);
  const float* crow = comb + (b * 8 + h) * 4096 + (i & 63) * 64;
  f32x4 breg[2][2];
  breg[0][0] = *(const f32x4*)(crow + g * 8);
  breg[0][1] = *(const f32x4*)(crow + g * 8 + 4);
  breg[1][0] = *(const f32x4*)(crow + 32 + g * 8);
  breg[1][1] = *(const f32x4*)(crow + 32 + g * 8 + 4);
  const bool ilow = i < 512;
  const int kp = 8 * (rr >> 2) + (rr & 3);
  const float scale = 0.17677669529663687f;
  float m_run = -1e30f, l_run = 0.0f;
  f32x4 o0 = {}, o1 = {};

  const bf16* krow = kbase + (kp << 5) + g * 8;
  const bf16* vrow0 = vbase + (rr << 10) + g * 8;
  const bf16* vrow1 = vbase + ((16 + rr) << 10) + g * 8;

  bf16x8 cK0 = *(const bf16x8*)(krow);
  bf16x8 cK1 = *(const bf16x8*)(krow + (4 << 5));
  bf16x8 cK2 = *(const bf16x8*)(krow + (32 << 5));
  bf16x8 cK3 = *(const bf16x8*)(krow + (36 << 5));

#pragma unroll
  for (int t = 0; t < 16; ++t) {
    const int kb = t * 64;
    bf16x8 v00 = *(const bf16x8*)(vrow0 + kb);
    bf16x8 v01 = *(const bf16x8*)(vrow0 + kb + 32);
    bf16x8 v10 = *(const bf16x8*)(vrow1 + kb);
    bf16x8 v11 = *(const bf16x8*)(vrow1 + kb + 32);
    bf16x8 nK0, nK1, nK2, nK3;
    if (t < 15) {
      const bf16* kn = krow + ((kb + 64) << 5);
      nK0 = *(const bf16x8*)(kn);
      nK1 = *(const bf16x8*)(kn + (4 << 5));
      nK2 = *(const bf16x8*)(kn + (32 << 5));
      nK3 = *(const bf16x8*)(kn + (36 << 5));
    } else {
      nK0 = cK0; nK1 = cK1; nK2 = cK2; nK3 = cK3;
    }
    f32x4 zero = {};
    f32x4 s0 = __builtin_amdgcn_mfma_f32_16x16x32_bf16(cK0, qfrag, zero, 0, 0, 0);
    f32x4 s1 = __builtin_amdgcn_mfma_f32_16x16x32_bf16(cK1, qfrag, zero, 0, 0, 0);
    f32x4 s2 = __builtin_amdgcn_mfma_f32_16x16x32_bf16(cK2, qfrag, zero, 0, 0, 0);
    f32x4 s3 = __builtin_amdgcn_mfma_f32_16x16x32_bf16(cK3, qfrag, zero, 0, 0, 0);
    const float madd = (win7 && (ilow != (kb < 512))) ? -100.0f : 0.0f;
    f32x4 v0, v1, v2, v3;
#pragma unroll
    for (int r = 0; r < 4; ++r) {
      v0[r] = s0[r] * scale + breg[0][0][r] + madd;
      v1[r] = s1[r] * scale + breg[0][1][r] + madd;
      v2[r] = s2[r] * scale + breg[1][0][r] + madd;
      v3[r] = s3[r] * scale + breg[1][1][r] + madd;
    }
    float m16 = fmaxf(fmaxf(fmaxf(fmaxf(v0[0], v0[1]), fmaxf(v0[2], v0[3])),
                            fmaxf(fmaxf(v1[0], v1[1]), fmaxf(v1[2], v1[3]))),
                      fmaxf(fmaxf(fmaxf(v2[0], v2[1]), fmaxf(v2[2], v2[3])),
                            fmaxf(fmaxf(v3[0], v3[1]), fmaxf(v3[2], v3[3]))));
    m16 = fmaxf(m16, __shfl_xor(m16, 16));
    m16 = fmaxf(m16, __shfl_xor(m16, 32));
    const float m_new = fmaxf(m_run, m16);
    const float corr = __expf(m_run - m_new);
    float p0[4], p1[4], p2[4], p3[4];
    float s16 = 0.0f;
#pragma unroll
    for (int r = 0; r < 4; ++r) {
      p0[r] = __expf(v0[r] - m_new); p1[r] = __expf(v1[r] - m_new);
      p2[r] = __expf(v2[r] - m_new); p3[r] = __expf(v3[r] - m_new);
      s16 += p0[r] + p1[r] + p2[r] + p3[r];
    }
    s16 += __shfl_xor(s16, 16);
    s16 += __shfl_xor(s16, 32);
    l_run = l_run * corr + s16;
    m_run = m_new;
    bf16x8 paL, paH;
#pragma unroll
    for (int r = 0; r < 4; ++r) {
      paL[r] = (bf16)p0[r]; paL[r + 4] = (bf16)p1[r];
      paH[r] = (bf16)p2[r]; paH[r + 4] = (bf16)p3[r];
    }
#pragma unroll
    for (int r = 0; r < 4; ++r) { o0[r] *= corr; o1[r] *= corr; }
    o0 = __builtin_amdgcn_mfma_f32_16x16x32_bf16(v00, paL, o0, 0, 0, 0);
    o0 = __builtin_amdgcn_mfma_f32_16x16x32_bf16(v01, paH, o0, 0, 0, 0);
    o1 = __builtin_amdgcn_mfma_f32_16x16x32_bf16(v10, paL, o1, 0, 0, 0);
    o1 = __builtin_amdgcn_mfma_f32_16x16x32_bf16(v11, paH, o1, 0, 0, 0);
    cK0 = nK0; cK1 = nK1; cK2 = nK2; cK3 = nK3;
  }
  const float inv = 1.0f / l_run;
  bf16* ybase = yws + (size_t)((wid << 10) + i) * 256 + h * 32;
  union { u16 us[4]; uint2 u2; } pk;
#pragma unroll
  for (int r = 0; r < 4; ++r) { bf16 bv = (bf16)(o0[r] * inv); pk.us[r] = *(const u16*)&bv; }
  *(uint2*)(ybase + g * 4) = pk.u2;
#pragma unroll
  for (int r = 0; r < 4; ++r) { bf16 bv = (bf16)(o1[r] * inv); pk.us[r] = *(const u16*)&bv; }
  *(uint2*)(ybase + 16 + g * 4) = pk.u2;
}

// ---------------- kernel 4: proj GEMM, m97-style, roll-back scatter ----------------
__global__ __launch_bounds__(256) void proj_k(const bf16* __restrict__ yws, const bf16* __restrict__ pwb,
                                              const float* __restrict__ pb, float* __restrict__ out) {
  __shared__ __align__(16) bf16 lA[128 * 64];
  __shared__ __align__(16) bf16 lB[128 * 64];
  const int lane = threadIdx.x & 63, wv = threadIdx.x >> 6;
  const int rr = lane & 15, g = lane >> 4;
  const int wr = wv >> 1, wc = wv & 1;
  const int bid = blockIdx.x;
  const int tt = (bid & 7) * 32 + (bid >> 3);
  const int mtile = tt >> 1, ntile = tt & 1;
  const int mb = mtile * 128, nb2 = ntile * 128;
  const int arow = lane >> 3;
  const int sg = ((lane & 7) ^ arow) << 3;
  const int axor = rr & 7;
  f32x4 acc[4][4] = {};
  for (int kb = 0; kb < 256; kb += 64) {
#pragma unroll
    for (int q = 0; q < 4; ++q) {
      const int rowp = (wv * 4 + q) * 8 + arow;
      glds16(yws + (size_t)(mb + rowp) * 256 + kb + sg, &lA[(wv * 4 + q) * 512]);
      glds16(pwb + (nb2 + rowp) * 256 + kb + sg, &lB[(wv * 4 + q) * 512]);
    }
    __syncthreads();
#pragma unroll
    for (int ks = 0; ks < 2; ++ks) {
      bf16x8 af[4], bfr[4];
#pragma unroll
      for (int rt = 0; rt < 4; ++rt)
        af[rt] = *(const bf16x8*)&lA[(wr * 64 + rt * 16 + rr) * 64 + (((ks << 2) | g) ^ axor) * 8];
#pragma unroll
      for (int ct = 0; ct < 4; ++ct)
        bfr[ct] = *(const bf16x8*)&lB[(wc * 64 + ct * 16 + rr) * 64 + (((ks << 2) | g) ^ axor) * 8];
#pragma unroll
      for (int rt = 0; rt < 4; ++rt)
#pragma unroll
        for (int ct = 0; ct < 4; ++ct)
          acc[rt][ct] = __builtin_amdgcn_mfma_f32_16x16x32_bf16(af[rt], bfr[ct], acc[rt][ct], 0, 0, 0);
    }
    __syncthreads();
  }
#pragma unroll
  for (int ct = 0; ct < 4; ++ct) {
    const int c2 = nb2 + wc * 64 + ct * 16 + rr;
    const float bc = pb[c2];
#pragma unroll
    for (int rt = 0; rt < 4; ++rt) {
#pragma unroll
      for (int r = 0; r < 4; ++r) {
        const int m = mb + wr * 64 + rt * 16 + g * 4 + r;
        const int wid = m >> 10, n = m & 1023;
        const int bb = wid >> 3;
        const int hh = ((wid & 7) * 64 + (n >> 4) + 32) & 511;  // roll(out, +32)
        out[(((bb * 512 + hh) * 16 + (n & 15)) << 8) + c2] = acc[rt][ct][r] + bc;
      }
    }
  }
}

extern "C" void kernel_launch(void* const* d_in, const int* in_sizes, int n_in,
                              void* d_out, int out_size, void* d_ws, size_t ws_size,
                              hipStream_t stream) {
  const float* x     = (const float*)d_in[0];
  const float* loc   = (const float*)d_in[1];
  const float* qkvw  = (const float*)d_in[2];
  const float* qkvb  = (const float*)d_in[3];
  const float* projw = (const float*)d_in[4];
  const float* projb = (const float*)d_in[5];
  const float* tt    = (const float*)d_in[6];
  const float* tx    = (const float*)d_in[7];
  const float* ty    = (const float*)d_in[8];
  const float* tz    = (const float*)d_in[9];
  char* ws = (char*)d_ws;
  bf16* qws   = (bf16*)(ws + OFF_Q);
  bf16* kws   = (bf16*)(ws + OFF_K);
  bf16* vtws  = (bf16*)(ws + OFF_VT);
  bf16* yws   = (bf16*)(ws + OFF_Y);
  bf16* xb    = (bf16*)(ws + OFF_Y);     // aliases yws; dead before attn writes
  float* comb = (float*)(ws + OFF_COMB);
  bf16* pwb   = (bf16*)(ws + OFF_PWB);
  bf16* wb    = (bf16*)(ws + OFF_WB);
  float* out = (float*)d_out;

  build_comb_k<<<16, 256, 0, stream>>>(loc, tt, tx, ty, tz, comb);
  cvt_x_k<<<2048, 256, 0, stream>>>(x, xb);
  cvt_w_k<<<128, 256, 0, stream>>>(qkvw, projw, wb, pwb);
  qkv_k<<<768, 256, 0, stream>>>(xb, wb, qkvb, qws, kws, vtws);
  attn_k<<<2048, 256, 0, stream>>>(qws, kws, vtws, comb, yws);
  proj_k<<<256, 256, 0, stream>>>(yws, pwb, projb, out);
}